// Round 3
// baseline (19648.416 us; speedup 1.0000x reference)
//
#include <hip/hip_runtime.h>
#include <math.h>

// ---------------------------------------------------------------------------
// R14: attack the REAL bottleneck. R13 post-mortem: WRITE_SIZE dropped as
// predicted but time didn't -> store path was never critical. Arithmetic:
// stage-3 issues 2688 ds_read_b128/CU/step (~32K cy on the shared LDS pipe)
// vs a 9.2K VALU floor -> the kernel is LDS-instruction-bound (VALUBusy 25%
// confirms). This round restructures every dot:
//   - wave = batch-slice: wave w owns batches [8w, 8w+8). H reads become
//     8-lane broadcasts (conflict-free), staging becomes wave-local (no
//     barriers around it), epilogue/projection stay intra-wave.
//   - lane tile: (4u x 8b) for H=256 stages, (2u x 8b) for H=128, over 1/8
//     of K (kl = lane&7; K-slices interleaved j4 = it*8+kl to spread banks).
//     LDS reads/CU/step for stage 3: 2688 -> 768.
//   - 3-level shfl_xor reduce-scatter combines K-partials (84 shuffles per
//     96 accs); final ownership = (1u x 4b)/lane = same epilogue shape.
//   - polls: wave0-only (R11-proven) + monotonic flag caching; prefetch
//     dropped (R13's 51ms modes). ring_store/hst kept (WRITE_SIZE win real).
// Transport semantics unchanged: sc0 sc1 LLC loads, agent-scope atomic
// stores, vmcnt(0)+barrier before flag. Bounded spins kept.
// ---------------------------------------------------------------------------

__device__ __forceinline__ float sigmoidf_(float v) {
    return 1.0f / (1.0f + __expf(-v));
}
__device__ __forceinline__ float tanhf_(float v) {
    float e = __expf(2.0f * v);
    return 1.0f - 2.0f / (e + 1.0f);
}

// src[(g*H+u)*J + j] -> dst[(u*3+g)*J + j]
__global__ void prep_k(const float* __restrict__ src, float* __restrict__ dst,
                       int H, int J) {
    int idx = blockIdx.x * 256 + threadIdx.x;
    int total = 3 * H * J;
    if (idx < total) {
        int g = idx / (H * J);
        int rem = idx - g * H * J;
        int u = rem / J;
        int j = rem - u * J;
        dst[(u * 3 + g) * J + j] = src[(g * H + u) * J + j];
    }
}

// ---- transport primitives --------------------------------------------------

__device__ __forceinline__ void flag_st(int* p, int v) {
    __hip_atomic_store(p, v, __ATOMIC_RELAXED, __HIP_MEMORY_SCOPE_AGENT);
}
__device__ __forceinline__ int flag_ld(const int* p) {
    return __hip_atomic_load(p, __ATOMIC_RELAXED, __HIP_MEMORY_SCOPE_AGENT);
}
__device__ __forceinline__ void ex_store(float* p, float v) {
    __hip_atomic_store(p, v, __ATOMIC_RELAXED, __HIP_MEMORY_SCOPE_AGENT);
}

// wave0-only poll with monotonic per-lane flag cache; barrier for the block.
__device__ __forceinline__ void pollwait(const int* p, int tgt, bool active,
                                         int& fc) {
    if (threadIdx.x < 64) {
        bool need = active && (fc < tgt);
        if (__any(need)) {
            int spins = 0;
            while (true) {
                if (need) { fc = flag_ld(p); need = (fc < tgt); }
                if (!__any(need)) break;
                if (++spins > 200000) break;  // degrade to absmax diagnostic
                __builtin_amdgcn_s_sleep(1);
            }
        }
    }
    __syncthreads();
}

// ---- wave-local ring staging (8 rows of J floats, wave-linear) ------------

template <int J>
__device__ __forceinline__ void stageW(float* dst, const float* src) {
    constexpr int NF4 = J / 32;  // (8*J/4)/64 float4 per lane
    const int lane = threadIdx.x & 63;
    float4 tmp[NF4];
    #pragma unroll
    for (int k = 0; k < NF4; ++k) {
        const float* p = src + (size_t)(k * 64 + lane) * 4;
        asm volatile("global_load_dwordx4 %0, %1, off sc0 sc1"
                     : "=v"(tmp[k]) : "v"(p) : "memory");
    }
    asm volatile("s_waitcnt vmcnt(0)" ::: "memory");
    #pragma unroll
    for (int k = 0; k < NF4; ++k)
        *(float4*)(dst + (k * 64 + lane) * 4) = tmp[k];
}

template <int J>
__device__ __forceinline__ void zeroW(float* dst) {
    const int lane = threadIdx.x & 63;
    #pragma unroll
    for (int k = 0; k < J / 32; ++k)
        *(float4*)(dst + (k * 64 + lane) * 4) = make_float4(0.f, 0.f, 0.f, 0.f);
}

// Coalesced ring store from the [32][U+4] hst tile (R13-proven: -23% WRITE).
template <int U, int J>
__device__ __forceinline__ void ring_store(float* hout, const float* hst) {
    constexpr int LU = (U == 32) ? 5 : 4;
    #pragma unroll
    for (int k = 0; k < (32 * U) / 256; ++k) {
        int i = k * 256 + threadIdx.x;
        int b = i >> LU;
        int c = i & (U - 1);
        ex_store(hout + b * J + c, hst[b * (U + 4) + c]);
    }
}

// ---- register-tiled, K-split dots -----------------------------------------
// Lane tile (TU u x 8 b), K-slice = kl (lane&7), slices interleaved mod 8.
// acc[g][f]: dotA4 (TU=4): g = u_local*2 + (b8>>2), f = ch*4 + (b8&3)
//            dotB2 (TU=2): g = u_local*4 + (b8>>1), f = ch*2 + (b8&1)

template <int J, int WST>
__device__ __forceinline__ void dotA4(const float* __restrict__ wb,
                                      const float* __restrict__ hb, int kl,
                                      float (&a)[8][12]) {
    #pragma unroll 2
    for (int it = 0; it < J / 32; ++it) {
        const int j = (it * 8 + kl) * 4;
        float4 h4[8];
        #pragma unroll
        for (int b = 0; b < 8; ++b)
            h4[b] = *(const float4*)(hb + b * J + j);
        #pragma unroll
        for (int i = 0; i < 4; ++i) {
            #pragma unroll
            for (int ch = 0; ch < 3; ++ch) {
                float4 w = *(const float4*)(wb + i * WST + ch * J + j);
                #pragma unroll
                for (int b8 = 0; b8 < 8; ++b8) {
                    float& acc = a[i * 2 + (b8 >> 2)][ch * 4 + (b8 & 3)];
                    acc = fmaf(w.x, h4[b8].x, acc);
                    acc = fmaf(w.y, h4[b8].y, acc);
                    acc = fmaf(w.z, h4[b8].z, acc);
                    acc = fmaf(w.w, h4[b8].w, acc);
                }
            }
        }
    }
}

template <int J, int WST>
__device__ __forceinline__ void dotB2(const float* __restrict__ wb,
                                      const float* __restrict__ hb, int kl,
                                      float (&a)[8][6]) {
    #pragma unroll 2
    for (int it = 0; it < J / 32; ++it) {
        const int j = (it * 8 + kl) * 4;
        float4 h4[8];
        #pragma unroll
        for (int b = 0; b < 8; ++b)
            h4[b] = *(const float4*)(hb + b * J + j);
        #pragma unroll
        for (int i = 0; i < 2; ++i) {
            #pragma unroll
            for (int ch = 0; ch < 3; ++ch) {
                float4 w = *(const float4*)(wb + i * WST + ch * J + j);
                #pragma unroll
                for (int b8 = 0; b8 < 8; ++b8) {
                    float& acc = a[i * 4 + (b8 >> 1)][ch * 2 + (b8 & 1)];
                    acc = fmaf(w.x, h4[b8].x, acc);
                    acc = fmaf(w.y, h4[b8].y, acc);
                    acc = fmaf(w.z, h4[b8].z, acc);
                    acc = fmaf(w.w, h4[b8].w, acc);
                }
            }
        }
    }
}

// Reduce-scatter across the 8 K-lanes (masks 1,2,4). Lane keeps group
// gf = 4*(kl&1) | 2*((kl>>1)&1) | ((kl>>2)&1); result lands in a[0][*].
template <int G, int F>
__device__ __forceinline__ void rscat(float (&a)[G][F], int kl) {
    #pragma unroll
    for (int lev = 0; (1 << lev) < G; ++lev) {
        const int m = 1 << lev;
        const int g = G >> (lev + 1);
        const bool hi = ((kl >> lev) & 1) != 0;
        #pragma unroll
        for (int gg = 0; gg < g; ++gg) {
            #pragma unroll
            for (int f = 0; f < F; ++f) {
                float give = hi ? a[gg][f] : a[gg + g][f];
                float got = __shfl_xor(give, m, 64);
                a[gg][f] = (hi ? a[gg + g][f] : a[gg][f]) + got;
            }
        }
    }
}

__global__ __launch_bounds__(256) void gru_pipe_kernel(
    const float* __restrict__ x,
    const float* __restrict__ w_ih1,
    const float* __restrict__ b_ih1, const float* __restrict__ b_hh1,
    const float* __restrict__ b_ih2, const float* __restrict__ b_hh2,
    const float* __restrict__ b_ih3, const float* __restrict__ b_hh3,
    const float* __restrict__ b_ih4, const float* __restrict__ b_hh4,
    const float* __restrict__ wA_hh1,  // [256][3][256]
    const float* __restrict__ wA_ih2,  // [128][3][256]
    const float* __restrict__ wA_hh2,  // [128][3][128]
    const float* __restrict__ wA_ih3,  // [128][3][128]
    const float* __restrict__ wA_hh3,  // [128][3][128]
    const float* __restrict__ wA_ih4,  // [256][3][128]
    const float* __restrict__ wA_hh4,  // [256][3][256]
    const float* __restrict__ w_out, const float* __restrict__ b_out,
    int* __restrict__ flags,  // [8 bg][4 stages x 32 ints]
    float* __restrict__ ex,   // [8 bg][98304] h rings
    float* __restrict__ out)  // [256][1024] pre-zeroed
{
    const int tid = threadIdx.x;
    const int lane = tid & 63;
    const int w = tid >> 6;          // wave = batch-slice (8 rows)
    const int usl = lane >> 3;       // unit-slot 0..7
    const int kl = lane & 7;         // K-slice 0..7
    const int gf = ((kl & 1) << 2) | (kl & 2) | ((kl >> 2) & 1);
    extern __shared__ float smem[];
    __shared__ float xs[32];

    const int bg = blockIdx.x & 7;
    const int rest = blockIdx.x >> 3;
    const int s = rest >> 3;             // stage 0..3
    const int us = rest & 7;             // unit slice 0..7

    int* fb = flags + bg * 128;
    int* arr_own = fb + s * 32;

    // wave0 poll assignments (R11-proven roles)
    const int* pT = arr_own; int dT = -1000000000; bool aT = false;
    const int* pM = arr_own; bool aM = false;
    if (tid < 8) {
        if (s > 0) { pT = fb + (s - 1) * 32 + tid; dT = 1; aT = true; }
        pM = arr_own + tid; aM = true;
    } else if (tid < 16) {
        if (s < 3) { pT = fb + (s + 1) * 32 + (tid - 8); dT = -3; aT = true; }
    }
    int fcT = 0, fcM = 0;

    float* exb = ex + (size_t)bg * 98304;
    float* h1r = exb;            // 4 x 32 x 256
    float* h2r = exb + 32768;    // 4 x 32 x 128
    float* h3r = exb + 49152;
    float* h4r = exb + 65536;

    if (s == 0) {
        // ---- layer 1: in=1 scalar, H=256; tile (4u x 8b) x KS8 ----
        float* wlds = smem;            // 32*772
        float* hprev = smem + 24704;   // 32*256
        float* hst = smem + 32896;     // 32*36
        {
            const float* srcw = wA_hh1 + (size_t)us * 32 * 768;
            for (int i = tid; i < 24576; i += 256) {
                int uu = i / 768, r = i - uu * 768;
                wlds[uu * 772 + r] = srcw[i];
            }
        }
        __syncthreads();
        const int u_sl = usl * 4 + (gf >> 1);   // 0..31
        const int bhi = gf & 1;
        const int u = us * 32 + u_sl;
        const float* wbh = wlds + usl * 4 * 772;
        const float* hbh = hprev + w * 2048;
        const float br = b_ih1[u] + b_hh1[u];
        const float bz = b_ih1[u + 256] + b_hh1[u + 256];
        const float bxn = b_ih1[u + 512];
        const float bhn = b_hh1[u + 512];
        const float wir = w_ih1[u], wiz = w_ih1[u + 256], win = w_ih1[u + 512];
        for (int t = 0; t < 1024; ++t) {
            pollwait(pT, t + dT, aT, fcT);     // downstream backpressure
            if (tid < 32) xs[tid] = x[(size_t)(bg * 32 + tid) * 1024 + t];
            pollwait(pM, t, aM, fcM);          // peers done t-1
            if (t > 0) stageW<256>(hprev + w * 2048,
                                   h1r + (size_t)((t - 1) & 3) * 8192 + w * 2048);
            else       zeroW<256>(hprev + w * 2048);
            float ah[8][12] = {};
            dotA4<256, 772>(wbh, hbh, kl, ah);
            rscat<8, 12>(ah, kl);
            float* hout = h1r + (size_t)(t & 3) * 8192;
            #pragma unroll
            for (int bl = 0; bl < 4; ++bl) {
                int b32 = w * 8 + bhi * 4 + bl;
                float xv = xs[b32];
                float rr = sigmoidf_(ah[0][bl] + br + xv * wir);
                float zz = sigmoidf_(ah[0][4 + bl] + bz + xv * wiz);
                float nn = tanhf_(xv * win + bxn + rr * (ah[0][8 + bl] + bhn));
                float hp = hprev[b32 * 256 + u];
                hst[b32 * 36 + u_sl] = (1.f - zz) * nn + zz * hp;
            }
            __syncthreads();
            ring_store<32, 256>(hout + us * 32, hst);
            asm volatile("s_waitcnt vmcnt(0)" ::: "memory");
            __syncthreads();
            if (tid == 0) flag_st(arr_own + us, t + 1);
        }
    } else if (s == 1) {
        // ---- layer 2: in=256, H=128; tile (2u x 8b) x KS8 ----
        float* wlds = smem;            // 16*388
        float* hin = smem + 6208;      // 32*256
        float* hprev = smem + 14400;   // 32*128
        float* hst = smem + 18496;     // 32*20
        {
            const float* srcw = wA_hh2 + (size_t)us * 16 * 384;
            for (int i = tid; i < 6144; i += 256) {
                int uu = i / 384, r = i - uu * 384;
                wlds[uu * 388 + r] = srcw[i];
            }
        }
        __syncthreads();
        const int u_sl = usl * 2 + (gf >> 2);   // 0..15
        const int bq = gf & 3;
        const int u = us * 16 + u_sl;
        const float* wbh = wlds + usl * 2 * 388;
        const float* wbi = wA_ih2 + (size_t)(us * 16 + usl * 2) * 768;
        const float* hbi = hin + w * 2048;
        const float* hbh = hprev + w * 1024;
        const float br = b_ih2[u] + b_hh2[u];
        const float bz = b_ih2[u + 128] + b_hh2[u + 128];
        const float bxn = b_ih2[u + 256];
        const float bhn = b_hh2[u + 256];
        for (int t = 0; t < 1024; ++t) {
            pollwait(pT, t + dT, aT, fcT);     // upstream >= t+1, down >= t-3
            stageW<256>(hin + w * 2048, h1r + (size_t)(t & 3) * 8192 + w * 2048);
            float ai[8][6] = {};
            dotB2<256, 768>(wbi, hbi, kl, ai);
            rscat<8, 6>(ai, kl);
            pollwait(pM, t, aM, fcM);
            if (t > 0) stageW<128>(hprev + w * 1024,
                                   h2r + (size_t)((t - 1) & 3) * 4096 + w * 1024);
            else       zeroW<128>(hprev + w * 1024);
            float ah[8][6] = {};
            dotB2<128, 388>(wbh, hbh, kl, ah);
            rscat<8, 6>(ah, kl);
            float* hout = h2r + (size_t)(t & 3) * 4096;
            #pragma unroll
            for (int bl = 0; bl < 2; ++bl) {
                int b32 = w * 8 + bq * 2 + bl;
                float rr = sigmoidf_(ai[0][bl] + ah[0][bl] + br);
                float zz = sigmoidf_(ai[0][2 + bl] + ah[0][2 + bl] + bz);
                float nn = tanhf_(ai[0][4 + bl] + bxn + rr * (ah[0][4 + bl] + bhn));
                float hp = hprev[b32 * 128 + u];
                hst[b32 * 20 + u_sl] = (1.f - zz) * nn + zz * hp;
            }
            __syncthreads();
            ring_store<16, 128>(hout + us * 16, hst);
            asm volatile("s_waitcnt vmcnt(0)" ::: "memory");
            __syncthreads();
            if (tid == 0) flag_st(arr_own + us, t + 1);
        }
    } else if (s == 2) {
        // ---- layer 3: in=128, H=128; tile (2u x 8b) x KS8 ----
        float* wlds = smem;            // 16*388
        float* hin = smem + 6208;      // 32*128
        float* hprev = smem + 10304;   // 32*128
        float* hst = smem + 14400;     // 32*20
        {
            const float* srcw = wA_hh3 + (size_t)us * 16 * 384;
            for (int i = tid; i < 6144; i += 256) {
                int uu = i / 384, r = i - uu * 384;
                wlds[uu * 388 + r] = srcw[i];
            }
        }
        __syncthreads();
        const int u_sl = usl * 2 + (gf >> 2);
        const int bq = gf & 3;
        const int u = us * 16 + u_sl;
        const float* wbh = wlds + usl * 2 * 388;
        const float* wbi = wA_ih3 + (size_t)(us * 16 + usl * 2) * 384;
        const float* hbi = hin + w * 1024;
        const float* hbh = hprev + w * 1024;
        const float br = b_ih3[u] + b_hh3[u];
        const float bz = b_ih3[u + 128] + b_hh3[u + 128];
        const float bxn = b_ih3[u + 256];
        const float bhn = b_hh3[u + 256];
        for (int t = 0; t < 1024; ++t) {
            pollwait(pT, t + dT, aT, fcT);
            stageW<128>(hin + w * 1024, h2r + (size_t)(t & 3) * 4096 + w * 1024);
            float ai[8][6] = {};
            dotB2<128, 384>(wbi, hbi, kl, ai);
            rscat<8, 6>(ai, kl);
            pollwait(pM, t, aM, fcM);
            if (t > 0) stageW<128>(hprev + w * 1024,
                                   h3r + (size_t)((t - 1) & 3) * 4096 + w * 1024);
            else       zeroW<128>(hprev + w * 1024);
            float ah[8][6] = {};
            dotB2<128, 388>(wbh, hbh, kl, ah);
            rscat<8, 6>(ah, kl);
            float* hout = h3r + (size_t)(t & 3) * 4096;
            #pragma unroll
            for (int bl = 0; bl < 2; ++bl) {
                int b32 = w * 8 + bq * 2 + bl;
                float rr = sigmoidf_(ai[0][bl] + ah[0][bl] + br);
                float zz = sigmoidf_(ai[0][2 + bl] + ah[0][2 + bl] + bz);
                float nn = tanhf_(ai[0][4 + bl] + bxn + rr * (ah[0][4 + bl] + bhn));
                float hp = hprev[b32 * 128 + u];
                hst[b32 * 20 + u_sl] = (1.f - zz) * nn + zz * hp;
            }
            __syncthreads();
            ring_store<16, 128>(hout + us * 16, hst);
            asm volatile("s_waitcnt vmcnt(0)" ::: "memory");
            __syncthreads();
            if (tid == 0) flag_st(arr_own + us, t + 1);
        }
    } else {
        // ---- layer 4: in=128, H=256; tile (4u x 8b) x KS8, + projection ----
        float* wlds = smem;            // 32*772
        float* hin = smem + 24704;     // 32*128
        float* hprev = smem + 28800;   // 32*256
        float* hst = smem + 36992;     // 32*36
        {
            const float* srcw = wA_hh4 + (size_t)us * 32 * 768;
            for (int i = tid; i < 24576; i += 256) {
                int uu = i / 768, r = i - uu * 768;
                wlds[uu * 772 + r] = srcw[i];
            }
        }
        __syncthreads();
        const int u_sl = usl * 4 + (gf >> 1);
        const int bhi = gf & 1;
        const int u = us * 32 + u_sl;
        const float* wbh = wlds + usl * 4 * 772;
        const float* wbi = wA_ih4 + (size_t)(us * 32 + usl * 4) * 384;
        const float* hbi = hin + w * 1024;
        const float* hbh = hprev + w * 2048;
        const float br = b_ih4[u] + b_hh4[u];
        const float bz = b_ih4[u + 256] + b_hh4[u + 256];
        const float bxn = b_ih4[u + 512];
        const float bhn = b_hh4[u + 512];
        const float wo = w_out[u];
        for (int t = 0; t < 1024; ++t) {
            pollwait(pT, t + dT, aT, fcT);   // upstream only
            stageW<128>(hin + w * 1024, h3r + (size_t)(t & 3) * 4096 + w * 1024);
            float ai[8][12] = {};
            dotA4<128, 384>(wbi, hbi, kl, ai);
            rscat<8, 12>(ai, kl);
            pollwait(pM, t, aM, fcM);
            if (t > 0) stageW<256>(hprev + w * 2048,
                                   h4r + (size_t)((t - 1) & 3) * 8192 + w * 2048);
            else       zeroW<256>(hprev + w * 2048);
            float ah[8][12] = {};
            dotA4<256, 772>(wbh, hbh, kl, ah);
            rscat<8, 12>(ah, kl);
            float* hout = h4r + (size_t)(t & 3) * 8192;
            float pk[4];
            #pragma unroll
            for (int bl = 0; bl < 4; ++bl) {
                int b32 = w * 8 + bhi * 4 + bl;
                float rr = sigmoidf_(ai[0][bl] + ah[0][bl] + br);
                float zz = sigmoidf_(ai[0][4 + bl] + ah[0][4 + bl] + bz);
                float nn = tanhf_(ai[0][8 + bl] + bxn + rr * (ah[0][8 + bl] + bhn));
                float hp = hprev[b32 * 256 + u];
                float hnew = (1.f - zz) * nn + zz * hp;
                hst[b32 * 36 + u_sl] = hnew;
                pk[bl] = wo * hnew;
            }
            // intra-wave projection: sum over units (lane bits 0,1,3,4,5)
            #pragma unroll
            for (int bl = 0; bl < 4; ++bl) {
                pk[bl] += __shfl_xor(pk[bl], 1, 64);
                pk[bl] += __shfl_xor(pk[bl], 2, 64);
                pk[bl] += __shfl_xor(pk[bl], 8, 64);
                pk[bl] += __shfl_xor(pk[bl], 16, 64);
                pk[bl] += __shfl_xor(pk[bl], 32, 64);
            }
            __syncthreads();
            ring_store<32, 256>(hout + us * 32, hst);
            asm volatile("s_waitcnt vmcnt(0)" ::: "memory");
            __syncthreads();
            if (tid == 0) flag_st(arr_own + us, t + 1);
            if ((lane & 59) == 0) {  // lanes 0 (bhi=0) and 4 (bhi=1) per wave
                #pragma unroll
                for (int bl = 0; bl < 4; ++bl) {
                    float v = pk[bl];
                    if (us == 0) v += b_out[0];
                    atomicAdd(out + (size_t)(bg * 32 + w * 8 + bhi * 4 + bl) * 1024 + t, v);
                }
            }
        }
    }
}

extern "C" void kernel_launch(void* const* d_in, const int* in_sizes, int n_in,
                              void* d_out, int out_size, void* d_ws, size_t ws_size,
                              hipStream_t stream) {
    const float* x     = (const float*)d_in[0];
    const float* w_ih1 = (const float*)d_in[1];
    const float* w_hh1 = (const float*)d_in[2];
    const float* b_ih1 = (const float*)d_in[3];
    const float* b_hh1 = (const float*)d_in[4];
    const float* w_ih2 = (const float*)d_in[5];
    const float* w_hh2 = (const float*)d_in[6];
    const float* b_ih2 = (const float*)d_in[7];
    const float* b_hh2 = (const float*)d_in[8];
    const float* w_ih3 = (const float*)d_in[9];
    const float* w_hh3 = (const float*)d_in[10];
    const float* b_ih3 = (const float*)d_in[11];
    const float* b_hh3 = (const float*)d_in[12];
    const float* w_ih4 = (const float*)d_in[13];
    const float* w_hh4 = (const float*)d_in[14];
    const float* b_ih4 = (const float*)d_in[15];
    const float* b_hh4 = (const float*)d_in[16];
    const float* w_out = (const float*)d_in[17];
    const float* b_out = (const float*)d_in[18];

    float* ws = (float*)d_ws;
    float* wA_hh1 = ws;                  // 196608
    float* wA_ih2 = wA_hh1 + 196608;     //  98304
    float* wA_hh2 = wA_ih2 + 98304;      //  49152
    float* wA_ih3 = wA_hh2 + 49152;      //  49152
    float* wA_hh3 = wA_ih3 + 49152;      //  49152
    float* wA_ih4 = wA_hh3 + 49152;      //  98304
    float* wA_hh4 = wA_ih4 + 98304;      // 196608
    float* ex     = wA_hh4 + 196608;     // 786432 (8 bg x 98304)
    int*   flags  = (int*)(ex + 786432); // 8 x 128 ints

    (void)hipMemsetAsync(flags, 0, 1024 * sizeof(int), stream);
    (void)hipMemsetAsync(d_out, 0, 256 * 1024 * sizeof(float), stream);

    prep_k<<<768, 256, 0, stream>>>(w_hh1, wA_hh1, 256, 256);
    prep_k<<<384, 256, 0, stream>>>(w_ih2, wA_ih2, 128, 256);
    prep_k<<<192, 256, 0, stream>>>(w_hh2, wA_hh2, 128, 128);
    prep_k<<<192, 256, 0, stream>>>(w_ih3, wA_ih3, 128, 128);
    prep_k<<<192, 256, 0, stream>>>(w_hh3, wA_hh3, 128, 128);
    prep_k<<<384, 256, 0, stream>>>(w_ih4, wA_ih4, 256, 128);
    prep_k<<<768, 256, 0, stream>>>(w_hh4, wA_hh4, 256, 256);

    // 149KB dynamic LDS (38144 floats): 1 block/CU; grid=256 => co-resident.
    const int dyn_lds = 38144 * (int)sizeof(float);
    (void)hipFuncSetAttribute((const void*)gru_pipe_kernel,
                              hipFuncAttributeMaxDynamicSharedMemorySize, dyn_lds);

    gru_pipe_kernel<<<256, 256, dyn_lds, stream>>>(
        x, w_ih1, b_ih1, b_hh1, b_ih2, b_hh2, b_ih3, b_hh3, b_ih4, b_hh4,
        wA_hh1, wA_ih2, wA_hh2, wA_ih3, wA_hh3, wA_ih4, wA_hh4,
        w_out, b_out, flags, ex, (float*)d_out);
}